// Round 9
// baseline (184.339 us; speedup 1.0000x reference)
//
#include <hip/hip_runtime.h>
#include <math.h>
#include <stdint.h>

typedef float f32x2 __attribute__((ext_vector_type(2)));

#define LTOT 64
#define GL   16           // lanes per wavelength
#define LPL  4            // layers per lane
#define NT   4            // tiles (of 4 wavelengths) per wave

#define INV2PI  0.15915494309189535f
#define LOG2E   1.4426950408889634f
#define LOG10_2 0.30102999566398120f

// complex value for a packed pair of chains: lo = sigma=+1, hi = sigma=-1
struct C2 { f32x2 r, i; };
// transfer matrix in factored form [[A, iB],[iC, D]]
struct M2 { C2 A, B, C, D; };

typedef __attribute__((address_space(3))) uint32_t lds_u32;
typedef __attribute__((address_space(1))) const uint32_t gbl_u32;

__device__ __forceinline__ f32x2 shx(f32x2 v, int m) {
    f32x2 r;
    r.x = __shfl_xor(v.x, m);
    r.y = __shfl_xor(v.y, m);
    return r;
}

// one layer for one stack, both sigmas packed: P = P @ M_layer (or P = M if first)
__device__ __forceinline__ void layer_stack(M2& M, bool first, float kd,
                                            float er, float ei, float kr, float ki) {
    // n0 = sqrt(eps) (principal, er>0, ei>=0), inv = 1/|n0|^2 = 1/|eps|
    float h2  = fmaf(er, er, ei * ei);
    float inv = __builtin_amdgcn_rsqf(h2);       // 1/|eps|
    float mm  = h2 * inv;                        // |eps|
    float x   = 0.5f * (mm + er);
    float rx  = __builtin_amdgcn_rsqf(x);
    float n0r = x * rx;
    float n0i = 0.5f * ei * rx;

    float ar = kd * n0r, ai = kd * n0i;   // a = kd * n0
    float br = kd * kr,  bi = kd * ki;    // b = kd * kappa (|br| <= ~0.024)

    // trig of a_r (native, revolutions); small-angle polys for b_r
    float rf = __builtin_amdgcn_fractf(ar * INV2PI);
    float sa = __builtin_amdgcn_sinf(rf);
    float ca = __builtin_amdgcn_cosf(rf);
    float b2 = br * br;
    float sb = br * fmaf(b2, -0.16666667f, 1.0f);
    float cb = fmaf(b2, -0.5f, 1.0f);
    float u = sa * cb, v = ca * sb, wq = ca * cb, zq = sa * sb;

    f32x2 S, Cx, Y;
    S.x = u + v;   S.y = u - v;     // sin(ar +/- br)
    Cx.x = wq - zq; Cx.y = wq + zq; // cos(ar +/- br)
    Y.x = ai + bi; Y.y = ai - bi;   // Im(delta), |Y| <= ~0.17

    // cosh/sinh by poly (err < 3e-8 on this range)
    f32x2 y2 = Y * Y;
    f32x2 ch = (y2 * 0.041666667f + 0.5f) * y2 + 1.0f;
    f32x2 sh = Y * ((y2 * 0.0083333333f + 0.16666667f) * y2 + 1.0f);

    // cos(delta) = (Cx*ch, -S*sh) ; sin(delta) = (S*ch, Cx*sh)
    f32x2 c_r = Cx * ch;
    f32x2 c_i = -(S * sh);
    f32x2 s_r = S * ch;
    f32x2 s_i = Cx * sh;

    // q = s * conj(n0) * inv  (so m01 = i q) ; p = n0 * s (so m10 = i p)
    f32x2 q_r = (s_r * n0r + s_i * n0i) * inv;
    f32x2 q_i = (s_i * n0r - s_r * n0i) * inv;
    f32x2 p_r = s_r * n0r - s_i * n0i;
    f32x2 p_i = s_i * n0r + s_r * n0i;

    if (first) {
        M.A.r = c_r; M.A.i = c_i;
        M.B.r = q_r; M.B.i = q_i;
        M.C.r = p_r; M.C.i = p_i;
        M.D.r = c_r; M.D.i = c_i;
    } else {
        // A' = A c - B p ; B' = A q + B c ; C' = C c + D p ; D' = D c - C q
        f32x2 nAr = M.A.r*c_r - M.A.i*c_i - M.B.r*p_r + M.B.i*p_i;
        f32x2 nAi = M.A.r*c_i + M.A.i*c_r - M.B.r*p_i - M.B.i*p_r;
        f32x2 nBr = M.A.r*q_r - M.A.i*q_i + M.B.r*c_r - M.B.i*c_i;
        f32x2 nBi = M.A.r*q_i + M.A.i*q_r + M.B.r*c_i + M.B.i*c_r;
        f32x2 nCr = M.C.r*c_r - M.C.i*c_i + M.D.r*p_r - M.D.i*p_i;
        f32x2 nCi = M.C.r*c_i + M.C.i*c_r + M.D.r*p_i + M.D.i*p_r;
        f32x2 nDr = M.D.r*c_r - M.D.i*c_i - M.C.r*q_r + M.C.i*q_i;
        f32x2 nDi = M.D.r*c_i + M.D.i*c_r - M.C.r*q_i - M.C.i*q_r;
        M.A.r = nAr; M.A.i = nAi; M.B.r = nBr; M.B.i = nBi;
        M.C.r = nCr; M.C.i = nCi; M.D.r = nDr; M.D.i = nDi;
    }
}

// L = L · R in factored form:
// A = Al Ar - Bl Cr ; B = Al Br + Bl Dr ; C = Cl Ar + Dl Cr ; D = Dl Dr - Cl Br
__device__ __forceinline__ void combine(M2& L, const M2& R) {
    f32x2 nAr = L.A.r*R.A.r - L.A.i*R.A.i - L.B.r*R.C.r + L.B.i*R.C.i;
    f32x2 nAi = L.A.r*R.A.i + L.A.i*R.A.r - L.B.r*R.C.i - L.B.i*R.C.r;
    f32x2 nBr = L.A.r*R.B.r - L.A.i*R.B.i + L.B.r*R.D.r - L.B.i*R.D.i;
    f32x2 nBi = L.A.r*R.B.i + L.A.i*R.B.r + L.B.r*R.D.i + L.B.i*R.D.r;
    f32x2 nCr = L.C.r*R.A.r - L.C.i*R.A.i + L.D.r*R.C.r - L.D.i*R.C.i;
    f32x2 nCi = L.C.r*R.A.i + L.C.i*R.A.r + L.D.r*R.C.i + L.D.i*R.C.r;
    f32x2 nDr = L.D.r*R.D.r - L.D.i*R.D.i - L.C.r*R.B.r + L.C.i*R.B.i;
    f32x2 nDi = L.D.r*R.D.i + L.D.i*R.D.r - L.C.r*R.B.i - L.C.i*R.B.r;
    L.A.r = nAr; L.A.i = nAi; L.B.r = nBr; L.B.i = nBi;
    L.C.r = nCr; L.C.i = nCi; L.D.r = nDr; L.D.i = nDi;
}

__device__ __forceinline__ M2 shfl_m2(const M2& M, int m) {
    M2 R;
    R.A.r = shx(M.A.r, m); R.A.i = shx(M.A.i, m);
    R.B.r = shx(M.B.r, m); R.B.i = shx(M.B.i, m);
    R.C.r = shx(M.C.r, m); R.C.i = shx(M.C.i, m);
    R.D.r = shx(M.D.r, m); R.D.i = shx(M.D.i, m);
    return R;
}

__global__ __launch_bounds__(256, 2) void chiral_kernel(
    const float* __restrict__ wl,  const float* __restrict__ thickP,
    const float* __restrict__ mindp, const float* __restrict__ maxdp,
    const float* __restrict__ ecr, const float* __restrict__ eci,
    const float* __restrict__ kcr, const float* __restrict__ kci,
    const float* __restrict__ ear, const float* __restrict__ eai,
    const float* __restrict__ kar, const float* __restrict__ kai,
    float* __restrict__ out, int W)
{
    // 64 KiB static LDS: [wave][buf][array][lane float4 slot]
    __shared__ float lds[4][2][8][256];

    const int tid  = threadIdx.x;
    const int v    = tid >> 6;     // wave within block
    const int lane = tid & 63;
    const int grp  = lane >> 4;    // which of 4 wavelengths in this wave-tile
    const int j    = lane & 15;    // lane owns layers 4j..4j+3

    const int wavegid = blockIdx.x * 4 + v;
    const int w0 = wavegid * (4 * NT);
    if (w0 >= W) return;

    // per-lane global element offset within one tile
    const size_t laneoff = (size_t)grp * LTOT + 4 * (size_t)j;

#define STAGE(buf, wbase) do {                                                            \
        size_t g_ = (size_t)(wbase) * LTOT + laneoff;                                     \
        float* dst_ = &lds[v][(buf)][0][0];                                               \
        __builtin_amdgcn_global_load_lds((gbl_u32*)(ecr + g_), (lds_u32*)(dst_ + 0*256), 16, 0, 0); \
        __builtin_amdgcn_global_load_lds((gbl_u32*)(eci + g_), (lds_u32*)(dst_ + 1*256), 16, 0, 0); \
        __builtin_amdgcn_global_load_lds((gbl_u32*)(kcr + g_), (lds_u32*)(dst_ + 2*256), 16, 0, 0); \
        __builtin_amdgcn_global_load_lds((gbl_u32*)(kci + g_), (lds_u32*)(dst_ + 3*256), 16, 0, 0); \
        __builtin_amdgcn_global_load_lds((gbl_u32*)(ear + g_), (lds_u32*)(dst_ + 4*256), 16, 0, 0); \
        __builtin_amdgcn_global_load_lds((gbl_u32*)(eai + g_), (lds_u32*)(dst_ + 5*256), 16, 0, 0); \
        __builtin_amdgcn_global_load_lds((gbl_u32*)(kar + g_), (lds_u32*)(dst_ + 6*256), 16, 0, 0); \
        __builtin_amdgcn_global_load_lds((gbl_u32*)(kai + g_), (lds_u32*)(dst_ + 7*256), 16, 0, 0); \
    } while (0)

    // prologue: stage tile 0 into buffer 0 (async, zero VGPR cost)
    STAGE(0, w0);
    float wlv = wl[w0 + grp];

    const float lo = mindp[0], hi = maxdp[0];
    float4 tp4 = *reinterpret_cast<const float4*>(thickP + LPL * j);
    const float* ptp = reinterpret_cast<const float*>(&tp4);
    float dq[LPL];
    #pragma unroll
    for (int q = 0; q < LPL; q++) {
        float sg = __builtin_amdgcn_rcpf(1.0f + __builtin_amdgcn_exp2f(-ptp[q] * LOG2E));
        dq[q] = fmaf(sg, hi - lo, lo) * 1e-9f;   // thickness, layer-only
    }

    #pragma unroll
    for (int t = 0; t < NT; t++) {
        const int cur = t & 1;
        const int w = w0 + 4 * t + grp;
        float k0 = 6.2831852e6f * __builtin_amdgcn_rcpf(wlv);

        // A: wait for this tile's staged data (issued one full compute phase ago,
        // except t=0), then pull it from LDS into registers.
        asm volatile("s_waitcnt vmcnt(0)" ::: "memory");
        __builtin_amdgcn_sched_barrier(0);
        const float* wb = &lds[v][cur][0][0];
        float4 Decr = *reinterpret_cast<const float4*>(wb + 0*256 + 4*lane);
        float4 Deci = *reinterpret_cast<const float4*>(wb + 1*256 + 4*lane);
        float4 Dkcr = *reinterpret_cast<const float4*>(wb + 2*256 + 4*lane);
        float4 Dkci = *reinterpret_cast<const float4*>(wb + 3*256 + 4*lane);
        float4 Dear = *reinterpret_cast<const float4*>(wb + 4*256 + 4*lane);
        float4 Deai = *reinterpret_cast<const float4*>(wb + 5*256 + 4*lane);
        float4 Dkar = *reinterpret_cast<const float4*>(wb + 6*256 + 4*lane);
        float4 Dkai = *reinterpret_cast<const float4*>(wb + 7*256 + 4*lane);

        // B: issue next tile's async loads — they fly during C's compute.
        if (t + 1 < NT) {
            STAGE(cur ^ 1, w0 + 4 * (t + 1));
            wlv = wl[w0 + 4 * (t + 1) + grp];
        }

        // C: layer chain + butterfly + store
        const float* pecr = reinterpret_cast<const float*>(&Decr);
        const float* peci = reinterpret_cast<const float*>(&Deci);
        const float* pkcr = reinterpret_cast<const float*>(&Dkcr);
        const float* pkci = reinterpret_cast<const float*>(&Dkci);
        const float* pear = reinterpret_cast<const float*>(&Dear);
        const float* peai = reinterpret_cast<const float*>(&Deai);
        const float* pkar = reinterpret_cast<const float*>(&Dkar);
        const float* pkai = reinterpret_cast<const float*>(&Dkai);

        M2 Mc, Ma;   // stack c, stack a (each holds sigma +/- packed)
        #pragma unroll
        for (int q = 0; q < LPL; q++) {
            bool first = (q == 0);
            float kd = k0 * dq[q];
            layer_stack(Mc, first, kd, pecr[q], peci[q], pkcr[q], pkci[q]);
            layer_stack(Ma, first, kd, pear[q], peai[q], pkar[q], pkai[q]);
        }

        // select-free ordered reduction across the 16 lanes of this group
        #pragma unroll
        for (int m = 1; m < GL; m <<= 1) {
            M2 Oc = shfl_m2(Mc, m);
            M2 Oa = shfl_m2(Ma, m);
            combine(Mc, Oc);
            combine(Ma, Oa);
        }

        if (j == 0 && w < W) {
            const float NOUT = 1.45f;
            // denom = A + i*NOUT*B + i*C + NOUT*D  (N_IN = 1)
            f32x2 drc = Mc.A.r + NOUT * Mc.D.r - NOUT * Mc.B.i - Mc.C.i;
            f32x2 dic = Mc.A.i + NOUT * Mc.D.i + NOUT * Mc.B.r + Mc.C.r;
            f32x2 dra = Ma.A.r + NOUT * Ma.D.r - NOUT * Ma.B.i - Ma.C.i;
            f32x2 dia = Ma.A.i + NOUT * Ma.D.i + NOUT * Ma.B.r + Ma.C.r;
            f32x2 denc = drc * drc + dic * dic;
            f32x2 dena = dra * dra + dia * dia;
            // T = 4*NOUT/|den|^2 = 5.8/|den|^2 ; A = -log10(T + 1e-12)
            float Arc = -LOG10_2 * __builtin_amdgcn_logf(5.8f * __builtin_amdgcn_rcpf(denc.x) + 1e-12f);
            float Alc = -LOG10_2 * __builtin_amdgcn_logf(5.8f * __builtin_amdgcn_rcpf(denc.y) + 1e-12f);
            float Ara = -LOG10_2 * __builtin_amdgcn_logf(5.8f * __builtin_amdgcn_rcpf(dena.x) + 1e-12f);
            float Ala = -LOG10_2 * __builtin_amdgcn_logf(5.8f * __builtin_amdgcn_rcpf(dena.y) + 1e-12f);

            const float SC = (2.0f * 0.87f - 1.0f) * 32980.0f;
            out[0 * W + w] = (Alc - Arc) * SC;   // cd_c * scale
            out[1 * W + w] = (Ala - Ara) * SC;   // cd_a * scale
            out[2 * W + w] = 0.5f * (Alc + Arc); // abs_c
            out[3 * W + w] = 0.5f * (Ala + Ara); // abs_a
        }
    }
#undef STAGE
}

extern "C" void kernel_launch(void* const* d_in, const int* in_sizes, int n_in,
                              void* d_out, int out_size, void* d_ws, size_t ws_size,
                              hipStream_t stream) {
    const float* wl     = (const float*)d_in[0];
    const float* thickP = (const float*)d_in[1];
    const float* mind   = (const float*)d_in[2];
    const float* maxd   = (const float*)d_in[3];
    const float* ecr    = (const float*)d_in[4];
    const float* eci    = (const float*)d_in[5];
    const float* kcr    = (const float*)d_in[6];
    const float* kci    = (const float*)d_in[7];
    const float* ear    = (const float*)d_in[8];
    const float* eai    = (const float*)d_in[9];
    const float* kar    = (const float*)d_in[10];
    const float* kai    = (const float*)d_in[11];
    float* out = (float*)d_out;

    int W = in_sizes[0];
    int wl_per_block = 4 * NT * 4;            // 4 waves * 4 wl/tile * NT tiles
    int grid = (W + wl_per_block - 1) / wl_per_block;
    chiral_kernel<<<grid, 256, 0, stream>>>(wl, thickP, mind, maxd,
                                            ecr, eci, kcr, kci,
                                            ear, eai, kar, kai, out, W);
}

// Round 11
// 180.225 us; speedup vs baseline: 1.0228x; 1.0228x over previous
//
#include <hip/hip_runtime.h>
#include <math.h>

typedef float f32x4 __attribute__((ext_vector_type(4)));

#define LTOT 64
#define GL   16           // lanes per wavelength-PAIR group
#define LPL  4            // layers per lane

#define INV2PI  0.15915494309189535f
#define LOG2E   1.4426950408889634f
#define LOG10_2 0.30102999566398120f

// packed 4 chains: (w0 sigma+, w0 sigma-, w1 sigma+, w1 sigma-)
struct C4 { f32x4 r, i; };
// transfer matrix in factored form [[A, iB],[iC, D]]
struct M4 { C4 A, B, C, D; };

__device__ __forceinline__ f32x4 shx4(f32x4 v, int m) {
    f32x4 r;
    r.x = __shfl_xor(v.x, m); r.y = __shfl_xor(v.y, m);
    r.z = __shfl_xor(v.z, m); r.w = __shfl_xor(v.w, m);
    return r;
}

// one layer, one stack, TWO wavelengths (4 chains packed):
// P = P @ M_layer (or P = M if first)
__device__ __forceinline__ void layer2(M4& M, bool first,
    float kd0, float kd1,
    float er0, float ei0, float kr0, float ki0,
    float er1, float ei1, float kr1, float ki1)
{
    // ---- wl 0 scalar prep ----
    float h20 = fmaf(er0, er0, ei0 * ei0);
    float iv0 = __builtin_amdgcn_rsqf(h20);      // 1/|eps|
    float mm0 = h20 * iv0;                       // |eps|
    float x0  = 0.5f * (mm0 + er0);
    float rx0 = __builtin_amdgcn_rsqf(x0);
    float n0r0 = x0 * rx0, n0i0 = 0.5f * ei0 * rx0;
    float ar0 = kd0 * n0r0, ai0 = kd0 * n0i0;
    float br0 = kd0 * kr0,  bi0 = kd0 * ki0;
    float rf0 = __builtin_amdgcn_fractf(ar0 * INV2PI);
    float sa0 = __builtin_amdgcn_sinf(rf0);
    float ca0 = __builtin_amdgcn_cosf(rf0);
    float b20 = br0 * br0;
    float sb0 = br0 * fmaf(b20, -0.16666667f, 1.0f);
    float cb0 = fmaf(b20, -0.5f, 1.0f);
    float u0 = sa0 * cb0, v0 = ca0 * sb0, cc0 = ca0 * cb0, zz0 = sa0 * sb0;

    // ---- wl 1 scalar prep ----
    float h21 = fmaf(er1, er1, ei1 * ei1);
    float iv1 = __builtin_amdgcn_rsqf(h21);
    float mm1 = h21 * iv1;
    float x1  = 0.5f * (mm1 + er1);
    float rx1 = __builtin_amdgcn_rsqf(x1);
    float n0r1 = x1 * rx1, n0i1 = 0.5f * ei1 * rx1;
    float ar1 = kd1 * n0r1, ai1 = kd1 * n0i1;
    float br1 = kd1 * kr1,  bi1 = kd1 * ki1;
    float rf1 = __builtin_amdgcn_fractf(ar1 * INV2PI);
    float sa1 = __builtin_amdgcn_sinf(rf1);
    float ca1 = __builtin_amdgcn_cosf(rf1);
    float b21 = br1 * br1;
    float sb1 = br1 * fmaf(b21, -0.16666667f, 1.0f);
    float cb1 = fmaf(b21, -0.5f, 1.0f);
    float u1 = sa1 * cb1, v1 = ca1 * sb1, cc1 = ca1 * cb1, zz1 = sa1 * sb1;

    // ---- assemble packed vectors ----
    f32x4 S  = { u0 + v0,  u0 - v0,  u1 + v1,  u1 - v1  };  // sin(ar +/- br)
    f32x4 Cx = { cc0 - zz0, cc0 + zz0, cc1 - zz1, cc1 + zz1 }; // cos(ar +/- br)
    f32x4 Y  = { ai0 + bi0, ai0 - bi0, ai1 + bi1, ai1 - bi1 }; // Im(delta)
    f32x4 Nr = { n0r0, n0r0, n0r1, n0r1 };
    f32x4 Ni = { n0i0, n0i0, n0i1, n0i1 };
    f32x4 IV = { iv0, iv0, iv1, iv1 };

    // cosh/sinh by poly (|Y| <= ~0.17, err < 3e-8)
    f32x4 y2 = Y * Y;
    f32x4 ch = (y2 * 0.041666667f + 0.5f) * y2 + 1.0f;
    f32x4 sh = Y * ((y2 * 0.0083333333f + 0.16666667f) * y2 + 1.0f);

    f32x4 c_r = Cx * ch;
    f32x4 c_i = -(S * sh);
    f32x4 s_r = S * ch;
    f32x4 s_i = Cx * sh;

    // q = s*conj(n0)/|n0|^2 (m01 = i q) ; p = n0*s (m10 = i p)
    f32x4 q_r = (s_r * Nr + s_i * Ni) * IV;
    f32x4 q_i = (s_i * Nr - s_r * Ni) * IV;
    f32x4 p_r = s_r * Nr - s_i * Ni;
    f32x4 p_i = s_i * Nr + s_r * Ni;

    if (first) {
        M.A.r = c_r; M.A.i = c_i;
        M.B.r = q_r; M.B.i = q_i;
        M.C.r = p_r; M.C.i = p_i;
        M.D.r = c_r; M.D.i = c_i;
    } else {
        // A' = A c - B p ; B' = A q + B c ; C' = C c + D p ; D' = D c - C q
        f32x4 nAr = M.A.r*c_r - M.A.i*c_i - M.B.r*p_r + M.B.i*p_i;
        f32x4 nAi = M.A.r*c_i + M.A.i*c_r - M.B.r*p_i - M.B.i*p_r;
        f32x4 nBr = M.A.r*q_r - M.A.i*q_i + M.B.r*c_r - M.B.i*c_i;
        f32x4 nBi = M.A.r*q_i + M.A.i*q_r + M.B.r*c_i + M.B.i*c_r;
        f32x4 nCr = M.C.r*c_r - M.C.i*c_i + M.D.r*p_r - M.D.i*p_i;
        f32x4 nCi = M.C.r*c_i + M.C.i*c_r + M.D.r*p_i + M.D.i*p_r;
        f32x4 nDr = M.D.r*c_r - M.D.i*c_i - M.C.r*q_r + M.C.i*q_i;
        f32x4 nDi = M.D.r*c_i + M.D.i*c_r - M.C.r*q_i - M.C.i*q_r;
        M.A.r = nAr; M.A.i = nAi; M.B.r = nBr; M.B.i = nBi;
        M.C.r = nCr; M.C.i = nCi; M.D.r = nDr; M.D.i = nDi;
    }
}

// L = L · R in factored form
__device__ __forceinline__ void combine4(M4& L, const M4& R) {
    f32x4 nAr = L.A.r*R.A.r - L.A.i*R.A.i - L.B.r*R.C.r + L.B.i*R.C.i;
    f32x4 nAi = L.A.r*R.A.i + L.A.i*R.A.r - L.B.r*R.C.i - L.B.i*R.C.r;
    f32x4 nBr = L.A.r*R.B.r - L.A.i*R.B.i + L.B.r*R.D.r - L.B.i*R.D.i;
    f32x4 nBi = L.A.r*R.B.i + L.A.i*R.B.r + L.B.r*R.D.i + L.B.i*R.D.r;
    f32x4 nCr = L.C.r*R.A.r - L.C.i*R.A.i + L.D.r*R.C.r - L.D.i*R.C.i;
    f32x4 nCi = L.C.r*R.A.i + L.C.i*R.A.r + L.D.r*R.C.i + L.D.i*R.C.r;
    f32x4 nDr = L.D.r*R.D.r - L.D.i*R.D.i - L.C.r*R.B.r + L.C.i*R.B.i;
    f32x4 nDi = L.D.r*R.D.i + L.D.i*R.D.r - L.C.r*R.B.i - L.C.i*R.B.r;
    L.A.r = nAr; L.A.i = nAi; L.B.r = nBr; L.B.i = nBi;
    L.C.r = nCr; L.C.i = nCi; L.D.r = nDr; L.D.i = nDi;
}

__device__ __forceinline__ M4 shfl_m4(const M4& M, int m) {
    M4 R;
    R.A.r = shx4(M.A.r, m); R.A.i = shx4(M.A.i, m);
    R.B.r = shx4(M.B.r, m); R.B.i = shx4(M.B.i, m);
    R.C.r = shx4(M.C.r, m); R.C.i = shx4(M.C.i, m);
    R.D.r = shx4(M.D.r, m); R.D.i = shx4(M.D.i, m);
    return R;
}

__global__ __launch_bounds__(256, 2) void chiral_kernel(
    const float* __restrict__ wl,  const float* __restrict__ thickP,
    const float* __restrict__ mindp, const float* __restrict__ maxdp,
    const float* __restrict__ ecr, const float* __restrict__ eci,
    const float* __restrict__ kcr, const float* __restrict__ kci,
    const float* __restrict__ ear, const float* __restrict__ eai,
    const float* __restrict__ kar, const float* __restrict__ kai,
    float* __restrict__ out, int W)
{
    int t = blockIdx.x * blockDim.x + threadIdx.x;
    int g = t >> 4;      // one 16-lane group per wavelength PAIR
    int j = t & 15;      // lane owns layers 4j..4j+3
    if (g >= (W >> 1)) return;
    int w0 = 2 * g, w1 = w0 + 1;

    size_t b0 = (size_t)w0 * LTOT + (size_t)(LPL * j);
    size_t b1 = b0 + LTOT;

    // per-lane loads: thickP (shared) + 8 arrays x 2 wavelengths
    float4 Ltp   = *reinterpret_cast<const float4*>(thickP + LPL * j);
    float4 Lecr0 = *reinterpret_cast<const float4*>(ecr + b0);
    float4 Leci0 = *reinterpret_cast<const float4*>(eci + b0);
    float4 Lkcr0 = *reinterpret_cast<const float4*>(kcr + b0);
    float4 Lkci0 = *reinterpret_cast<const float4*>(kci + b0);
    float4 Lear0 = *reinterpret_cast<const float4*>(ear + b0);
    float4 Leai0 = *reinterpret_cast<const float4*>(eai + b0);
    float4 Lkar0 = *reinterpret_cast<const float4*>(kar + b0);
    float4 Lkai0 = *reinterpret_cast<const float4*>(kai + b0);
    float4 Lecr1 = *reinterpret_cast<const float4*>(ecr + b1);
    float4 Leci1 = *reinterpret_cast<const float4*>(eci + b1);
    float4 Lkcr1 = *reinterpret_cast<const float4*>(kcr + b1);
    float4 Lkci1 = *reinterpret_cast<const float4*>(kci + b1);
    float4 Lear1 = *reinterpret_cast<const float4*>(ear + b1);
    float4 Leai1 = *reinterpret_cast<const float4*>(eai + b1);
    float4 Lkar1 = *reinterpret_cast<const float4*>(kar + b1);
    float4 Lkai1 = *reinterpret_cast<const float4*>(kai + b1);

    float lo = mindp[0], hi = maxdp[0];
    float k00 = 6.2831852e6f * __builtin_amdgcn_rcpf(wl[w0]);
    float k01 = 6.2831852e6f * __builtin_amdgcn_rcpf(wl[w1]);

    const float* ptp = reinterpret_cast<const float*>(&Ltp);
    float dq[LPL];
    #pragma unroll
    for (int q = 0; q < LPL; q++) {
        float sg = __builtin_amdgcn_rcpf(1.0f + __builtin_amdgcn_exp2f(-ptp[q] * LOG2E));
        dq[q] = fmaf(sg, hi - lo, lo) * 1e-9f;
    }

    const float* pecr0 = reinterpret_cast<const float*>(&Lecr0);
    const float* peci0 = reinterpret_cast<const float*>(&Leci0);
    const float* pkcr0 = reinterpret_cast<const float*>(&Lkcr0);
    const float* pkci0 = reinterpret_cast<const float*>(&Lkci0);
    const float* pear0 = reinterpret_cast<const float*>(&Lear0);
    const float* peai0 = reinterpret_cast<const float*>(&Leai0);
    const float* pkar0 = reinterpret_cast<const float*>(&Lkar0);
    const float* pkai0 = reinterpret_cast<const float*>(&Lkai0);
    const float* pecr1 = reinterpret_cast<const float*>(&Lecr1);
    const float* peci1 = reinterpret_cast<const float*>(&Leci1);
    const float* pkcr1 = reinterpret_cast<const float*>(&Lkcr1);
    const float* pkci1 = reinterpret_cast<const float*>(&Lkci1);
    const float* pear1 = reinterpret_cast<const float*>(&Lear1);
    const float* peai1 = reinterpret_cast<const float*>(&Leai1);
    const float* pkar1 = reinterpret_cast<const float*>(&Lkar1);
    const float* pkai1 = reinterpret_cast<const float*>(&Lkai1);

    M4 Mc, Ma;   // stack c, stack a — each packs (w0+, w0-, w1+, w1-)

    #pragma unroll
    for (int q = 0; q < LPL; q++) {
        bool first = (q == 0);
        float kd0 = k00 * dq[q];
        float kd1 = k01 * dq[q];
        layer2(Mc, first, kd0, kd1,
               pecr0[q], peci0[q], pkcr0[q], pkci0[q],
               pecr1[q], peci1[q], pkcr1[q], pkci1[q]);
        layer2(Ma, first, kd0, kd1,
               pear0[q], peai0[q], pkar0[q], pkai0[q],
               pear1[q], peai1[q], pkar1[q], pkai1[q]);
    }

    // select-free ordered butterfly: lane 0 ends with the full product
    #pragma unroll
    for (int m = 1; m < GL; m <<= 1) {
        M4 Oc = shfl_m4(Mc, m);
        combine4(Mc, Oc);
        M4 Oa = shfl_m4(Ma, m);
        combine4(Ma, Oa);
    }

    if (j == 0) {
        const float NOUT = 1.45f;
        // denom = A + i*NOUT*B + i*C + NOUT*D  (N_IN = 1)
        f32x4 drc = Mc.A.r + NOUT * Mc.D.r - NOUT * Mc.B.i - Mc.C.i;
        f32x4 dic = Mc.A.i + NOUT * Mc.D.i + NOUT * Mc.B.r + Mc.C.r;
        f32x4 dra = Ma.A.r + NOUT * Ma.D.r - NOUT * Ma.B.i - Ma.C.i;
        f32x4 dia = Ma.A.i + NOUT * Ma.D.i + NOUT * Ma.B.r + Ma.C.r;
        f32x4 denc = drc * drc + dic * dic;
        f32x4 dena = dra * dra + dia * dia;
        // A = -log10(5.8/|den|^2 + 1e-12)
#define ALOG(d) (-LOG10_2 * __builtin_amdgcn_logf(5.8f * __builtin_amdgcn_rcpf(d) + 1e-12f))
        float Arc0 = ALOG(denc.x), Alc0 = ALOG(denc.y);
        float Arc1 = ALOG(denc.z), Alc1 = ALOG(denc.w);
        float Ara0 = ALOG(dena.x), Ala0 = ALOG(dena.y);
        float Ara1 = ALOG(dena.z), Ala1 = ALOG(dena.w);
#undef ALOG
        const float SC = (2.0f * 0.87f - 1.0f) * 32980.0f;
        out[0 * W + w0] = (Alc0 - Arc0) * SC;
        out[0 * W + w1] = (Alc1 - Arc1) * SC;
        out[1 * W + w0] = (Ala0 - Ara0) * SC;
        out[1 * W + w1] = (Ala1 - Ara1) * SC;
        out[2 * W + w0] = 0.5f * (Alc0 + Arc0);
        out[2 * W + w1] = 0.5f * (Alc1 + Arc1);
        out[3 * W + w0] = 0.5f * (Ala0 + Ara0);
        out[3 * W + w1] = 0.5f * (Ala1 + Ara1);
    }
}

extern "C" void kernel_launch(void* const* d_in, const int* in_sizes, int n_in,
                              void* d_out, int out_size, void* d_ws, size_t ws_size,
                              hipStream_t stream) {
    const float* wl     = (const float*)d_in[0];
    const float* thickP = (const float*)d_in[1];
    const float* mind   = (const float*)d_in[2];
    const float* maxd   = (const float*)d_in[3];
    const float* ecr    = (const float*)d_in[4];
    const float* eci    = (const float*)d_in[5];
    const float* kcr    = (const float*)d_in[6];
    const float* kci    = (const float*)d_in[7];
    const float* ear    = (const float*)d_in[8];
    const float* eai    = (const float*)d_in[9];
    const float* kar    = (const float*)d_in[10];
    const float* kai    = (const float*)d_in[11];
    float* out = (float*)d_out;

    int W = in_sizes[0];
    long long threads = (long long)(W / 2) * GL;   // 16 lanes per wavelength pair
    int block = 256;
    int grid = (int)((threads + block - 1) / block);
    chiral_kernel<<<grid, block, 0, stream>>>(wl, thickP, mind, maxd,
                                              ecr, eci, kcr, kci,
                                              ear, eai, kar, kai, out, W);
}